// Round 7
// baseline (719.872 us; speedup 1.0000x reference)
//
#include <hip/hip_runtime.h>

#define EMBED 1024
#define BATCH 4
#define SEQ   4096
#define ROWS  (BATCH*SEQ)   // 16384
#define CAP   192           // candidate slots per row
#define TSCAN_I 4235        // scan keep-margin in int units (~320 scaled logits)
#define TRES  300.0f        // rescore margin, scaled logits (covers i8 scan error band)
#define DEQ   0.0755640f    // int accum -> scaled logit: (6500/127)*(6/127)/32
#define QXS   21.166667f    // 127/6.0
#define QTS   0.01953846f   // 127/6500

typedef __attribute__((ext_vector_type(8))) short bf16x8;
typedef __attribute__((ext_vector_type(4))) float f32x4;
typedef __attribute__((ext_vector_type(4))) int   i32x4;

static __device__ __forceinline__ unsigned short f2bf(float x) {
    unsigned u = __float_as_uint(x);
    u = (u + 0x7fffu + ((u >> 16) & 1u)) >> 16;
    return (unsigned short)u;
}
static __device__ __forceinline__ float bf2f(unsigned short h) {
    return __uint_as_float(((unsigned)h) << 16);
}
static __device__ __forceinline__ void split2(float x, unsigned short& hi, unsigned short& lo) {
    hi = f2bf(x);
    lo = f2bf(x - bf2f(hi));
}
static __device__ __forceinline__ int q8(float x, float s) {
    int q = __float2int_rn(x * s);
    return q > 127 ? 127 : (q < -127 ? -127 : q);
}

// ---- async global->LDS staging, 128x32-short tile, 4-segment swizzle (r3-proven, 0 conflicts) ----
static __device__ __forceinline__ void stage_tile(unsigned short (*lds)[32],
                                                  const unsigned short* gbase,
                                                  int wave, int lane) {
#pragma unroll
    for (int c = 0; c < 2; c++) {
        int L = wave * 128 + c * 64 + lane;   // linear segment index 0..511
        int r = L >> 2, s = L & 3;
        int g = (s - (r >> 1)) & 3;
        __builtin_amdgcn_global_load_lds(
            (const __attribute__((address_space(1))) unsigned int*)(gbase + (size_t)r * EMBED + g * 8),
            (__attribute__((address_space(3))) unsigned int*)(&lds[r][s * 8]),
            16, 0, 0);
    }
}
static __device__ __forceinline__ bf16x8 read_frag(const unsigned short (*lds)[32], int r, int kq) {
    int s = ((kq >> 3) + (r >> 1)) & 3;
    return *(const bf16x8*)&lds[r][s * 8];
}

// ---------------- prep: wv_bar[i] = mean_d Wv[i][d] ----------------
__global__ void k_wvbar(const float* __restrict__ Wv, float* __restrict__ wvbar) {
    int r = blockIdx.x, t = threadIdx.x;
    float s = 0.f;
    for (int c = t; c < EMBED; c += 256) s += Wv[(size_t)r * EMBED + c];
    for (int d = 1; d < 64; d <<= 1) s += __shfl_xor(s, d);
    __shared__ float ws_[4];
    if ((t & 63) == 0) ws_[t >> 6] = s;
    __syncthreads();
    if (t == 0) wvbar[r] = (ws_[0] + ws_[1] + ws_[2] + ws_[3]) * (1.0f / EMBED);
}

// ---------------- prep: row split (+i8 quant) + vmean[r] = X[r,:].wvbar ----------------
__global__ __launch_bounds__(256) void k_xsplit_vmean(
    const float* __restrict__ X, const float* __restrict__ wvbar,
    unsigned short* __restrict__ Xhi, unsigned short* __restrict__ Xlo,
    signed char* __restrict__ Xi8, float* __restrict__ vmean) {
    int row = blockIdx.x, t = threadIdx.x;
    float4 x4 = *(const float4*)(X + (size_t)row * EMBED + t * 4);
    float4 w4 = *(const float4*)(wvbar + t * 4);
    ushort4 h, l;
    split2(x4.x, h.x, l.x); split2(x4.y, h.y, l.y);
    split2(x4.z, h.z, l.z); split2(x4.w, h.w, l.w);
    *(ushort4*)(Xhi + (size_t)row * EMBED + t * 4) = h;
    *(ushort4*)(Xlo + (size_t)row * EMBED + t * 4) = l;
    int q0 = q8(x4.x, QXS), q1 = q8(x4.y, QXS), q2 = q8(x4.z, QXS), q3 = q8(x4.w, QXS);
    int packed = (q0 & 0xff) | ((q1 & 0xff) << 8) | ((q2 & 0xff) << 16) | ((q3 & 0xff) << 24);
    *(int*)(Xi8 + (size_t)row * EMBED + t * 4) = packed;
    float s = x4.x * w4.x + x4.y * w4.y + x4.z * w4.z + x4.w * w4.w;
    for (int d = 1; d < 64; d <<= 1) s += __shfl_xor(s, d);
    __shared__ float ws_[4];
    if ((t & 63) == 0) ws_[t >> 6] = s;
    __syncthreads();
    if (t == 0) vmean[row] = ws_[0] + ws_[1] + ws_[2] + ws_[3];
}

// ---------------- split-bf16 GEMM: C[row][col] = sum_k A[row][k]*B[col][k] ----------------
__global__ __launch_bounds__(256) void k_gemm3(
    const unsigned short* __restrict__ Ahi, const unsigned short* __restrict__ Alo,
    const unsigned short* __restrict__ BThi, const unsigned short* __restrict__ BTlo,
    unsigned short* __restrict__ Chi, unsigned short* __restrict__ Clo) {
    __shared__ unsigned short Ah[128][32], Al[128][32], Bh[128][32], Bl[128][32];
    int bx = blockIdx.x;
    int bm = bx >> 3, bn = bx & 7;
    int tid = threadIdx.x, wave = tid >> 6, lane = tid & 63;
    int wm = (wave >> 1) * 64, wn = (wave & 1) * 64;
    int mrow = lane & 15, kq = (lane >> 4) * 8;

    f32x4 zero = {0.f, 0.f, 0.f, 0.f};
    f32x4 acc[4][4];
    for (int a = 0; a < 4; a++) for (int b = 0; b < 4; b++) acc[a][b] = zero;

    const unsigned short* Abase_h = Ahi + (size_t)(bm * 128) * EMBED;
    const unsigned short* Abase_l = Alo + (size_t)(bm * 128) * EMBED;
    const unsigned short* Bbase_h = BThi + (size_t)(bn * 128) * EMBED;
    const unsigned short* Bbase_l = BTlo + (size_t)(bn * 128) * EMBED;

    for (int k0 = 0; k0 < EMBED; k0 += 32) {
        __syncthreads();
        stage_tile(Ah, Abase_h + k0, wave, lane);
        stage_tile(Al, Abase_l + k0, wave, lane);
        stage_tile(Bh, Bbase_h + k0, wave, lane);
        stage_tile(Bl, Bbase_l + k0, wave, lane);
        __syncthreads();
        bf16x8 ah[4], al[4], bh[4], bl[4];
#pragma unroll
        for (int t = 0; t < 4; t++) {
            ah[t] = read_frag(Ah, wm + t * 16 + mrow, kq);
            al[t] = read_frag(Al, wm + t * 16 + mrow, kq);
            bh[t] = read_frag(Bh, wn + t * 16 + mrow, kq);
            bl[t] = read_frag(Bl, wn + t * 16 + mrow, kq);
        }
#pragma unroll
        for (int mt = 0; mt < 4; mt++)
#pragma unroll
            for (int nt = 0; nt < 4; nt++) {
                acc[mt][nt] = __builtin_amdgcn_mfma_f32_16x16x32_bf16(ah[mt], bh[nt], acc[mt][nt], 0, 0, 0);
                acc[mt][nt] = __builtin_amdgcn_mfma_f32_16x16x32_bf16(ah[mt], bl[nt], acc[mt][nt], 0, 0, 0);
                acc[mt][nt] = __builtin_amdgcn_mfma_f32_16x16x32_bf16(al[mt], bh[nt], acc[mt][nt], 0, 0, 0);
            }
    }
#pragma unroll
    for (int mt = 0; mt < 4; mt++)
#pragma unroll
        for (int nt = 0; nt < 4; nt++)
#pragma unroll
            for (int i = 0; i < 4; i++) {
                int row = bm * 128 + wm + mt * 16 + (lane >> 4) * 4 + i;
                int col = bn * 128 + wn + nt * 16 + (lane & 15);
                unsigned short h, l; split2(acc[mt][nt][i], h, l);
                Chi[(size_t)row * EMBED + col] = h;
                Clo[(size_t)row * EMBED + col] = l;
            }
}

// ---------------- gemm3 variant that additionally writes an i8-quantized copy of C ----------------
__global__ __launch_bounds__(256) void k_gemm3q(
    const unsigned short* __restrict__ Ahi, const unsigned short* __restrict__ Alo,
    const unsigned short* __restrict__ BThi, const unsigned short* __restrict__ BTlo,
    unsigned short* __restrict__ Chi, unsigned short* __restrict__ Clo,
    signed char* __restrict__ Ci8) {
    __shared__ unsigned short Ah[128][32], Al[128][32], Bh[128][32], Bl[128][32];
    int bx = blockIdx.x;
    int bm = bx >> 3, bn = bx & 7;
    int tid = threadIdx.x, wave = tid >> 6, lane = tid & 63;
    int wm = (wave >> 1) * 64, wn = (wave & 1) * 64;
    int mrow = lane & 15, kq = (lane >> 4) * 8;

    f32x4 zero = {0.f, 0.f, 0.f, 0.f};
    f32x4 acc[4][4];
    for (int a = 0; a < 4; a++) for (int b = 0; b < 4; b++) acc[a][b] = zero;

    const unsigned short* Abase_h = Ahi + (size_t)(bm * 128) * EMBED;
    const unsigned short* Abase_l = Alo + (size_t)(bm * 128) * EMBED;
    const unsigned short* Bbase_h = BThi + (size_t)(bn * 128) * EMBED;
    const unsigned short* Bbase_l = BTlo + (size_t)(bn * 128) * EMBED;

    for (int k0 = 0; k0 < EMBED; k0 += 32) {
        __syncthreads();
        stage_tile(Ah, Abase_h + k0, wave, lane);
        stage_tile(Al, Abase_l + k0, wave, lane);
        stage_tile(Bh, Bbase_h + k0, wave, lane);
        stage_tile(Bl, Bbase_l + k0, wave, lane);
        __syncthreads();
        bf16x8 ah[4], al[4], bh[4], bl[4];
#pragma unroll
        for (int t = 0; t < 4; t++) {
            ah[t] = read_frag(Ah, wm + t * 16 + mrow, kq);
            al[t] = read_frag(Al, wm + t * 16 + mrow, kq);
            bh[t] = read_frag(Bh, wn + t * 16 + mrow, kq);
            bl[t] = read_frag(Bl, wn + t * 16 + mrow, kq);
        }
#pragma unroll
        for (int mt = 0; mt < 4; mt++)
#pragma unroll
            for (int nt = 0; nt < 4; nt++) {
                acc[mt][nt] = __builtin_amdgcn_mfma_f32_16x16x32_bf16(ah[mt], bh[nt], acc[mt][nt], 0, 0, 0);
                acc[mt][nt] = __builtin_amdgcn_mfma_f32_16x16x32_bf16(ah[mt], bl[nt], acc[mt][nt], 0, 0, 0);
                acc[mt][nt] = __builtin_amdgcn_mfma_f32_16x16x32_bf16(al[mt], bh[nt], acc[mt][nt], 0, 0, 0);
            }
    }
#pragma unroll
    for (int mt = 0; mt < 4; mt++)
#pragma unroll
        for (int nt = 0; nt < 4; nt++)
#pragma unroll
            for (int i = 0; i < 4; i++) {
                int row = bm * 128 + wm + mt * 16 + (lane >> 4) * 4 + i;
                int col = bn * 128 + wn + nt * 16 + (lane & 15);
                float v = acc[mt][nt][i];
                unsigned short h, l; split2(v, h, l);
                Chi[(size_t)row * EMBED + col] = h;
                Clo[(size_t)row * EMBED + col] = l;
                Ci8[(size_t)row * EMBED + col] = (signed char)q8(v, QTS);
            }
}

// ---------------- zero candidate counters ----------------
__global__ void k_zero(int* __restrict__ p) {
    p[blockIdx.x * 256 + threadIdx.x] = 0;
}

// ---------------- scan: barrier-free direct-to-register i8, 128x128 block (2x2 waves of 64x64) ----
__global__ __launch_bounds__(256, 3) void k_scan(
    const signed char* __restrict__ Ti8, const signed char* __restrict__ Xi8,
    int* __restrict__ cnt, int2* __restrict__ cand) {
    __shared__ int wtm[2][128];
    int qb = blockIdx.x;   // 0..31
    int kb = blockIdx.y;   // 0..31
    int b  = blockIdx.z;   // 0..3
    int tid = threadIdx.x, wave = tid >> 6, lane = tid & 63;
    int wq = (wave >> 1) * 64, wk = (wave & 1) * 64;
    int mrow = lane & 15, seg = lane >> 4;
    size_t qrow0 = (size_t)b * SEQ + (size_t)qb * 128 + wq;
    size_t krow0 = (size_t)b * SEQ + (size_t)kb * 128 + wk;

    // per-lane fragment base pointers (i8 MFMA layout verified on HW in r6):
    // lane reads row (tile*16 + mrow), bytes [seg*16, seg*16+16) of each 64B chunk
    const signed char* Ab[4];
    const signed char* Bb[4];
#pragma unroll
    for (int t = 0; t < 4; t++) {
        Ab[t] = Ti8 + (qrow0 + t * 16 + mrow) * EMBED + seg * 16;
        Bb[t] = Xi8 + (krow0 + t * 16 + mrow) * EMBED + seg * 16;
    }

    i32x4 zero = {0, 0, 0, 0};
    i32x4 acc[4][4];
    for (int a = 0; a < 4; a++) for (int c = 0; c < 4; c++) acc[a][c] = zero;

    i32x4 a0[4], b0[4], a1[4], b1[4];
#pragma unroll
    for (int t = 0; t < 4; t++) {
        a0[t] = *(const i32x4*)(Ab[t]);
        b0[t] = *(const i32x4*)(Bb[t]);
    }
    // ping-pong over 16 chunks of 64 bytes; no barriers -> compiler emits fine vmcnt waits
    for (int c = 0; c < 16; c += 2) {
#pragma unroll
        for (int t = 0; t < 4; t++) {
            a1[t] = *(const i32x4*)(Ab[t] + (c + 1) * 64);
            b1[t] = *(const i32x4*)(Bb[t] + (c + 1) * 64);
        }
#pragma unroll
        for (int mt = 0; mt < 4; mt++)
#pragma unroll
            for (int nt = 0; nt < 4; nt++)
                acc[mt][nt] = __builtin_amdgcn_mfma_i32_16x16x64_i8(a0[mt], b0[nt], acc[mt][nt], 0, 0, 0);
        if (c + 2 < 16) {
#pragma unroll
            for (int t = 0; t < 4; t++) {
                a0[t] = *(const i32x4*)(Ab[t] + (c + 2) * 64);
                b0[t] = *(const i32x4*)(Bb[t] + (c + 2) * 64);
            }
        }
#pragma unroll
        for (int mt = 0; mt < 4; mt++)
#pragma unroll
            for (int nt = 0; nt < 4; nt++)
                acc[mt][nt] = __builtin_amdgcn_mfma_i32_16x16x64_i8(a1[mt], b1[nt], acc[mt][nt], 0, 0, 0);
    }

    // ---- epilogue: per-row local max (128-key block locality), collect candidates ----
    int tmax[4][4];
#pragma unroll
    for (int mt = 0; mt < 4; mt++)
#pragma unroll
        for (int i = 0; i < 4; i++) {
            int v = max(max(acc[mt][0][i], acc[mt][1][i]), max(acc[mt][2][i], acc[mt][3][i]));
#pragma unroll
            for (int d = 1; d < 16; d <<= 1) v = max(v, __shfl_xor(v, d));
            tmax[mt][i] = v;
        }
    if ((lane & 15) == 0) {
#pragma unroll
        for (int mt = 0; mt < 4; mt++)
#pragma unroll
            for (int i = 0; i < 4; i++)
                wtm[wave & 1][wq + mt * 16 + (lane >> 4) * 4 + i] = tmax[mt][i];
    }
    __syncthreads();
#pragma unroll
    for (int mt = 0; mt < 4; mt++)
#pragma unroll
        for (int i = 0; i < 4; i++) {
            int rl = wq + mt * 16 + (lane >> 4) * 4 + i;
            int th = max(wtm[0][rl], wtm[1][rl]) - TSCAN_I;
#pragma unroll
            for (int nt = 0; nt < 4; nt++) {
                int v = acc[mt][nt][i];
                if (v >= th) {
                    int grow = (int)((size_t)b * SEQ + (size_t)qb * 128) + rl;
                    int gcol = (int)krow0 + nt * 16 + (lane & 15);
                    int idx = atomicAdd(&cnt[grow], 1);
                    if (idx < CAP)
                        cand[(size_t)grow * CAP + idx] = make_int2(gcol, __float_as_int((float)v * DEQ));
                }
            }
        }
}

// ---------------- rescore: exact logits for survivors (T row . X key row), softmax ----------------
__global__ __launch_bounds__(64) void k_rescore(
    const unsigned short* __restrict__ Thi, const unsigned short* __restrict__ Tlo,
    const float* __restrict__ X, const float* __restrict__ vmean,
    const int* __restrict__ cnt, const int2* __restrict__ cand,
    float* __restrict__ out) {
    int row = blockIdx.x;
    int lane = threadIdx.x;
    int c = cnt[row]; if (c > CAP) c = CAP;
    const int2* cl = cand + (size_t)row * CAP;

    float smax = -INFINITY;
    for (int j = lane; j < c; j += 64) smax = fmaxf(smax, __int_as_float(cl[j].y));
    for (int d = 1; d < 64; d <<= 1) smax = fmaxf(smax, __shfl_xor(smax, d));
    float th = smax - TRES;

    // T row (exact hi+lo) into registers: dims [lane*16, lane*16+16)
    float q[16];
    {
        const unsigned short* qh = Thi + (size_t)row * EMBED + lane * 16;
        const unsigned short* ql = Tlo + (size_t)row * EMBED + lane * 16;
        bf16x8 h0 = *(const bf16x8*)qh, h1 = *(const bf16x8*)(qh + 8);
        bf16x8 l0 = *(const bf16x8*)ql, l1 = *(const bf16x8*)(ql + 8);
#pragma unroll
        for (int i = 0; i < 8; i++) {
            q[i]     = bf2f((unsigned short)h0[i]) + bf2f((unsigned short)l0[i]);
            q[i + 8] = bf2f((unsigned short)h1[i]) + bf2f((unsigned short)l1[i]);
        }
    }

    __shared__ int   sm_[CAP];
    __shared__ float sl_[CAP];
    __shared__ int   ns_;
    if (lane == 0) ns_ = 0;
    __syncthreads();
    for (int j = lane; j < c; j += 64) {
        int2 p = cl[j];
        if (__int_as_float(p.y) >= th) {
            int idx = atomicAdd(&ns_, 1);
            sm_[idx] = p.x;
        }
    }
    __syncthreads();
    int ns = ns_;
    for (int t = 0; t < ns; t++) {
        int m = sm_[t];
        const float* xr = X + (size_t)m * EMBED + lane * 16;
        float4 a0 = *(const float4*)(xr);
        float4 a1 = *(const float4*)(xr + 4);
        float4 a2 = *(const float4*)(xr + 8);
        float4 a3 = *(const float4*)(xr + 12);
        float dp = q[0]*a0.x + q[1]*a0.y + q[2]*a0.z + q[3]*a0.w
                 + q[4]*a1.x + q[5]*a1.y + q[6]*a1.z + q[7]*a1.w
                 + q[8]*a2.x + q[9]*a2.y + q[10]*a2.z + q[11]*a2.w
                 + q[12]*a3.x + q[13]*a3.y + q[14]*a3.z + q[15]*a3.w;
        for (int d = 1; d < 64; d <<= 1) dp += __shfl_xor(dp, d);
        if (lane == 0) sl_[t] = dp * 0.03125f;
    }
    __syncthreads();
    if (lane == 0) {
        float lm = -INFINITY;
        for (int t = 0; t < ns; t++) lm = fmaxf(lm, sl_[t]);
        float den = 0.f, num = 0.f;
        for (int t = 0; t < ns; t++) {
            float e = __expf(sl_[t] - lm);
            den += e;
            num += e * vmean[sm_[t]];
        }
        out[row] = num / den;
    }
}

extern "C" void kernel_launch(void* const* d_in, const int* in_sizes, int n_in,
                              void* d_out, int out_size, void* d_ws, size_t ws_size,
                              hipStream_t stream) {
    const float* X  = (const float*)d_in[0];
    const float* Wq = (const float*)d_in[1];
    const float* Wk = (const float*)d_in[2];
    const float* Wv = (const float*)d_in[3];
    float* out = (float*)d_out;

    char* p = (char*)d_ws;
    auto alloc = [&](size_t bytes) -> void* {
        void* q = (void*)p;
        p += (bytes + 255) & ~(size_t)255;
        return q;
    };
    unsigned short* Wqhi = (unsigned short*)alloc((size_t)EMBED * EMBED * 2);
    unsigned short* Wqlo = (unsigned short*)alloc((size_t)EMBED * EMBED * 2);
    unsigned short* Wkhi = (unsigned short*)alloc((size_t)EMBED * EMBED * 2);
    unsigned short* Wklo = (unsigned short*)alloc((size_t)EMBED * EMBED * 2);
    unsigned short* MThi = (unsigned short*)alloc((size_t)EMBED * EMBED * 2);
    unsigned short* MTlo = (unsigned short*)alloc((size_t)EMBED * EMBED * 2);
    unsigned short* Xhi  = (unsigned short*)alloc((size_t)ROWS * EMBED * 2);
    unsigned short* Xlo  = (unsigned short*)alloc((size_t)ROWS * EMBED * 2);
    unsigned short* Thi  = (unsigned short*)alloc((size_t)ROWS * EMBED * 2);
    unsigned short* Tlo  = (unsigned short*)alloc((size_t)ROWS * EMBED * 2);
    signed char*    Xi8  = (signed char*)alloc((size_t)ROWS * EMBED);
    signed char*    Ti8  = (signed char*)alloc((size_t)ROWS * EMBED);
    float* wvbar = (float*)alloc(EMBED * 4);
    float* vmean = (float*)alloc((size_t)ROWS * 4);
    int*   cnt   = (int*)alloc((size_t)ROWS * 4);
    int2*  cand  = (int2*)alloc((size_t)ROWS * CAP * 8);

    k_wvbar<<<EMBED, 256, 0, stream>>>(Wv, wvbar);
    // Row splits of the ORIGINAL Wq/Wk (M contraction is over the contiguous output dim).
    // vmean + Ti8 args are scratch here (overwritten later).
    k_xsplit_vmean<<<EMBED, 256, 0, stream>>>(Wq, wvbar, Wqhi, Wqlo, Ti8, vmean);
    k_xsplit_vmean<<<EMBED, 256, 0, stream>>>(Wk, wvbar, Wkhi, Wklo, Ti8, vmean);
    // M^T[b][a] = sum_n Wk[b][n]*Wq[a][n]
    k_gemm3<<<64, 256, 0, stream>>>(Wkhi, Wklo, Wqhi, Wqlo, MThi, MTlo);
    k_xsplit_vmean<<<ROWS, 256, 0, stream>>>(X, wvbar, Xhi, Xlo, Xi8, vmean);   // real vmean + Xi8
    k_gemm3q<<<1024, 256, 0, stream>>>(Xhi, Xlo, MThi, MTlo, Thi, Tlo, Ti8);    // T = X.M (+ Ti8)
    k_zero<<<ROWS / 256, 256, 0, stream>>>(cnt);
    k_scan<<<dim3(32, 32, 4), 256, 0, stream>>>(Ti8, Xi8, cnt, cand);
    k_rescore<<<ROWS, 64, 0, stream>>>(Thi, Tlo, X, vmean, cnt, cand, out);
}

// Round 8
// 595.114 us; speedup vs baseline: 1.2096x; 1.2096x over previous
//
#include <hip/hip_runtime.h>

#define EMBED 1024
#define BATCH 4
#define SEQ   4096
#define ROWS  (BATCH*SEQ)   // 16384
#define CAP   192           // candidate slots per row
#define TSCAN_I 4235        // scan keep-margin in int units (~320 scaled logits)
#define TRES  300.0f        // rescore margin, scaled logits (covers i8 scan error band)
#define DEQ   0.0755640f    // int accum -> scaled logit: (6500/127)*(6/127)/32
#define QXS   21.166667f    // 127/6.0
#define QTS   0.01953846f   // 127/6500

typedef __attribute__((ext_vector_type(8))) short bf16x8;
typedef __attribute__((ext_vector_type(4))) float f32x4;
typedef __attribute__((ext_vector_type(4))) int   i32x4;

static __device__ __forceinline__ unsigned short f2bf(float x) {
    unsigned u = __float_as_uint(x);
    u = (u + 0x7fffu + ((u >> 16) & 1u)) >> 16;
    return (unsigned short)u;
}
static __device__ __forceinline__ float bf2f(unsigned short h) {
    return __uint_as_float(((unsigned)h) << 16);
}
static __device__ __forceinline__ void split2(float x, unsigned short& hi, unsigned short& lo) {
    hi = f2bf(x);
    lo = f2bf(x - bf2f(hi));
}
static __device__ __forceinline__ int q8(float x, float s) {
    int q = __float2int_rn(x * s);
    return q > 127 ? 127 : (q < -127 ? -127 : q);
}

// ---- async global->LDS staging, 128x32-short tile, 4-segment swizzle (r3-proven, 0 conflicts) ----
static __device__ __forceinline__ void stage_tile(unsigned short (*lds)[32],
                                                  const unsigned short* gbase,
                                                  int wave, int lane) {
#pragma unroll
    for (int c = 0; c < 2; c++) {
        int L = wave * 128 + c * 64 + lane;   // linear segment index 0..511
        int r = L >> 2, s = L & 3;
        int g = (s - (r >> 1)) & 3;
        __builtin_amdgcn_global_load_lds(
            (const __attribute__((address_space(1))) unsigned int*)(gbase + (size_t)r * EMBED + g * 8),
            (__attribute__((address_space(3))) unsigned int*)(&lds[r][s * 8]),
            16, 0, 0);
    }
}
static __device__ __forceinline__ bf16x8 read_frag(const unsigned short (*lds)[32], int r, int kq) {
    int s = ((kq >> 3) + (r >> 1)) & 3;
    return *(const bf16x8*)&lds[r][s * 8];
}

// ---- i8 variant: 128x64-byte tile — identical byte addresses to the proven layout (r6-proven) ----
static __device__ __forceinline__ void stage_i8(signed char (*lds)[64],
                                                const signed char* gbase,
                                                int wave, int lane) {
#pragma unroll
    for (int c = 0; c < 2; c++) {
        int L = wave * 128 + c * 64 + lane;   // segment index 0..511
        int r = L >> 2, s = L & 3;
        int g = (s - (r >> 1)) & 3;
        __builtin_amdgcn_global_load_lds(
            (const __attribute__((address_space(1))) unsigned int*)(gbase + (size_t)r * EMBED + g * 16),
            (__attribute__((address_space(3))) unsigned int*)(&lds[r][s * 16]),
            16, 0, 0);
    }
}
static __device__ __forceinline__ i32x4 read_frag_i8(const signed char (*lds)[64], int r, int seg) {
    int s = (seg + (r >> 1)) & 3;
    return *(const i32x4*)&lds[r][s * 16];
}

// ---------------- prep: wv_bar[i] = mean_d Wv[i][d] ----------------
__global__ void k_wvbar(const float* __restrict__ Wv, float* __restrict__ wvbar) {
    int r = blockIdx.x, t = threadIdx.x;
    float s = 0.f;
    for (int c = t; c < EMBED; c += 256) s += Wv[(size_t)r * EMBED + c];
    for (int d = 1; d < 64; d <<= 1) s += __shfl_xor(s, d);
    __shared__ float ws_[4];
    if ((t & 63) == 0) ws_[t >> 6] = s;
    __syncthreads();
    if (t == 0) wvbar[r] = (ws_[0] + ws_[1] + ws_[2] + ws_[3]) * (1.0f / EMBED);
}

// ---------------- prep: row split (+i8 quant) + vmean[r] = X[r,:].wvbar ----------------
__global__ __launch_bounds__(256) void k_xsplit_vmean(
    const float* __restrict__ X, const float* __restrict__ wvbar,
    unsigned short* __restrict__ Xhi, unsigned short* __restrict__ Xlo,
    signed char* __restrict__ Xi8, float* __restrict__ vmean) {
    int row = blockIdx.x, t = threadIdx.x;
    float4 x4 = *(const float4*)(X + (size_t)row * EMBED + t * 4);
    float4 w4 = *(const float4*)(wvbar + t * 4);
    ushort4 h, l;
    split2(x4.x, h.x, l.x); split2(x4.y, h.y, l.y);
    split2(x4.z, h.z, l.z); split2(x4.w, h.w, l.w);
    *(ushort4*)(Xhi + (size_t)row * EMBED + t * 4) = h;
    *(ushort4*)(Xlo + (size_t)row * EMBED + t * 4) = l;
    int q0 = q8(x4.x, QXS), q1 = q8(x4.y, QXS), q2 = q8(x4.z, QXS), q3 = q8(x4.w, QXS);
    int packed = (q0 & 0xff) | ((q1 & 0xff) << 8) | ((q2 & 0xff) << 16) | ((q3 & 0xff) << 24);
    *(int*)(Xi8 + (size_t)row * EMBED + t * 4) = packed;
    float s = x4.x * w4.x + x4.y * w4.y + x4.z * w4.z + x4.w * w4.w;
    for (int d = 1; d < 64; d <<= 1) s += __shfl_xor(s, d);
    __shared__ float ws_[4];
    if ((t & 63) == 0) ws_[t >> 6] = s;
    __syncthreads();
    if (t == 0) vmean[row] = ws_[0] + ws_[1] + ws_[2] + ws_[3];
}

// ---------------- split-bf16 GEMM: C[row][col] = sum_k A[row][k]*B[col][k] ----------------
__global__ __launch_bounds__(256) void k_gemm3(
    const unsigned short* __restrict__ Ahi, const unsigned short* __restrict__ Alo,
    const unsigned short* __restrict__ BThi, const unsigned short* __restrict__ BTlo,
    unsigned short* __restrict__ Chi, unsigned short* __restrict__ Clo) {
    __shared__ unsigned short Ah[128][32], Al[128][32], Bh[128][32], Bl[128][32];
    int bx = blockIdx.x;
    int bm = bx >> 3, bn = bx & 7;
    int tid = threadIdx.x, wave = tid >> 6, lane = tid & 63;
    int wm = (wave >> 1) * 64, wn = (wave & 1) * 64;
    int mrow = lane & 15, kq = (lane >> 4) * 8;

    f32x4 zero = {0.f, 0.f, 0.f, 0.f};
    f32x4 acc[4][4];
    for (int a = 0; a < 4; a++) for (int b = 0; b < 4; b++) acc[a][b] = zero;

    const unsigned short* Abase_h = Ahi + (size_t)(bm * 128) * EMBED;
    const unsigned short* Abase_l = Alo + (size_t)(bm * 128) * EMBED;
    const unsigned short* Bbase_h = BThi + (size_t)(bn * 128) * EMBED;
    const unsigned short* Bbase_l = BTlo + (size_t)(bn * 128) * EMBED;

    for (int k0 = 0; k0 < EMBED; k0 += 32) {
        __syncthreads();
        stage_tile(Ah, Abase_h + k0, wave, lane);
        stage_tile(Al, Abase_l + k0, wave, lane);
        stage_tile(Bh, Bbase_h + k0, wave, lane);
        stage_tile(Bl, Bbase_l + k0, wave, lane);
        __syncthreads();
        bf16x8 ah[4], al[4], bh[4], bl[4];
#pragma unroll
        for (int t = 0; t < 4; t++) {
            ah[t] = read_frag(Ah, wm + t * 16 + mrow, kq);
            al[t] = read_frag(Al, wm + t * 16 + mrow, kq);
            bh[t] = read_frag(Bh, wn + t * 16 + mrow, kq);
            bl[t] = read_frag(Bl, wn + t * 16 + mrow, kq);
        }
#pragma unroll
        for (int mt = 0; mt < 4; mt++)
#pragma unroll
            for (int nt = 0; nt < 4; nt++) {
                acc[mt][nt] = __builtin_amdgcn_mfma_f32_16x16x32_bf16(ah[mt], bh[nt], acc[mt][nt], 0, 0, 0);
                acc[mt][nt] = __builtin_amdgcn_mfma_f32_16x16x32_bf16(ah[mt], bl[nt], acc[mt][nt], 0, 0, 0);
                acc[mt][nt] = __builtin_amdgcn_mfma_f32_16x16x32_bf16(al[mt], bh[nt], acc[mt][nt], 0, 0, 0);
            }
    }
#pragma unroll
    for (int mt = 0; mt < 4; mt++)
#pragma unroll
        for (int nt = 0; nt < 4; nt++)
#pragma unroll
            for (int i = 0; i < 4; i++) {
                int row = bm * 128 + wm + mt * 16 + (lane >> 4) * 4 + i;
                int col = bn * 128 + wn + nt * 16 + (lane & 15);
                unsigned short h, l; split2(acc[mt][nt][i], h, l);
                Chi[(size_t)row * EMBED + col] = h;
                Clo[(size_t)row * EMBED + col] = l;
            }
}

// ---------------- gemm3 variant that additionally writes an i8-quantized copy of C ----------------
__global__ __launch_bounds__(256) void k_gemm3q(
    const unsigned short* __restrict__ Ahi, const unsigned short* __restrict__ Alo,
    const unsigned short* __restrict__ BThi, const unsigned short* __restrict__ BTlo,
    unsigned short* __restrict__ Chi, unsigned short* __restrict__ Clo,
    signed char* __restrict__ Ci8) {
    __shared__ unsigned short Ah[128][32], Al[128][32], Bh[128][32], Bl[128][32];
    int bx = blockIdx.x;
    int bm = bx >> 3, bn = bx & 7;
    int tid = threadIdx.x, wave = tid >> 6, lane = tid & 63;
    int wm = (wave >> 1) * 64, wn = (wave & 1) * 64;
    int mrow = lane & 15, kq = (lane >> 4) * 8;

    f32x4 zero = {0.f, 0.f, 0.f, 0.f};
    f32x4 acc[4][4];
    for (int a = 0; a < 4; a++) for (int b = 0; b < 4; b++) acc[a][b] = zero;

    const unsigned short* Abase_h = Ahi + (size_t)(bm * 128) * EMBED;
    const unsigned short* Abase_l = Alo + (size_t)(bm * 128) * EMBED;
    const unsigned short* Bbase_h = BThi + (size_t)(bn * 128) * EMBED;
    const unsigned short* Bbase_l = BTlo + (size_t)(bn * 128) * EMBED;

    for (int k0 = 0; k0 < EMBED; k0 += 32) {
        __syncthreads();
        stage_tile(Ah, Abase_h + k0, wave, lane);
        stage_tile(Al, Abase_l + k0, wave, lane);
        stage_tile(Bh, Bbase_h + k0, wave, lane);
        stage_tile(Bl, Bbase_l + k0, wave, lane);
        __syncthreads();
        bf16x8 ah[4], al[4], bh[4], bl[4];
#pragma unroll
        for (int t = 0; t < 4; t++) {
            ah[t] = read_frag(Ah, wm + t * 16 + mrow, kq);
            al[t] = read_frag(Al, wm + t * 16 + mrow, kq);
            bh[t] = read_frag(Bh, wn + t * 16 + mrow, kq);
            bl[t] = read_frag(Bl, wn + t * 16 + mrow, kq);
        }
#pragma unroll
        for (int mt = 0; mt < 4; mt++)
#pragma unroll
            for (int nt = 0; nt < 4; nt++) {
                acc[mt][nt] = __builtin_amdgcn_mfma_f32_16x16x32_bf16(ah[mt], bh[nt], acc[mt][nt], 0, 0, 0);
                acc[mt][nt] = __builtin_amdgcn_mfma_f32_16x16x32_bf16(ah[mt], bl[nt], acc[mt][nt], 0, 0, 0);
                acc[mt][nt] = __builtin_amdgcn_mfma_f32_16x16x32_bf16(al[mt], bh[nt], acc[mt][nt], 0, 0, 0);
            }
    }
#pragma unroll
    for (int mt = 0; mt < 4; mt++)
#pragma unroll
        for (int nt = 0; nt < 4; nt++)
#pragma unroll
            for (int i = 0; i < 4; i++) {
                int row = bm * 128 + wm + mt * 16 + (lane >> 4) * 4 + i;
                int col = bn * 128 + wn + nt * 16 + (lane & 15);
                float v = acc[mt][nt][i];
                unsigned short h, l; split2(v, h, l);
                Chi[(size_t)row * EMBED + col] = h;
                Clo[(size_t)row * EMBED + col] = l;
                Ci8[(size_t)row * EMBED + col] = (signed char)q8(v, QTS);
            }
}

// ---------------- zero candidate counters ----------------
__global__ void k_zero(int* __restrict__ p) {
    p[blockIdx.x * 256 + threadIdx.x] = 0;
}

// ---------------- scan: i8 128x128, TRIPLE-buffered LDS, raw barrier + vmcnt(4) prefetch ----------------
__global__ __launch_bounds__(256) void k_scan(
    const signed char* __restrict__ Ti8, const signed char* __restrict__ Xi8,
    int* __restrict__ cnt, int2* __restrict__ cand) {
    __shared__ signed char Ts[3][128][64], Xs[3][128][64];   // 3 slots x (8KB T + 8KB X) = 48 KB
    __shared__ int wtm[2][128];
    int qb = blockIdx.x;   // 0..31
    int kb = blockIdx.y;   // 0..31
    int b  = blockIdx.z;   // 0..3
    int tid = threadIdx.x, wave = tid >> 6, lane = tid & 63;
    int wm = (wave >> 1) * 64, wn = (wave & 1) * 64;
    int mrow = lane & 15, seg = lane >> 4;
    size_t qrow0 = (size_t)b * SEQ + (size_t)qb * 128;
    size_t krow0 = (size_t)b * SEQ + (size_t)kb * 128;

    const signed char* Tbase = Ti8 + qrow0 * EMBED;
    const signed char* Xbase = Xi8 + krow0 * EMBED;

    i32x4 zero = {0, 0, 0, 0};
    i32x4 acc[4][4];
    for (int a = 0; a < 4; a++) for (int c = 0; c < 4; c++) acc[a][c] = zero;

    // prologue: stage chunk 0 into slot 0 (4 DMA instrs/thread)
    stage_i8(Ts[0], Tbase, wave, lane);
    stage_i8(Xs[0], Xbase, wave, lane);

    for (int c = 0; c < 16; c++) {
        // prefetch chunk c+1 into slot (c+1)%3 (slot (c+1)%3 was consumed at iter c-2: 2 barriers ago -> race-free)
        if (c + 1 < 16) {
            stage_i8(Ts[(c + 1) % 3], Tbase + (c + 1) * 64, wave, lane);
            stage_i8(Xs[(c + 1) % 3], Xbase + (c + 1) * 64, wave, lane);
            // wait only the OLDER 4 DMAs (chunk c); leave chunk c+1's 4 in flight
            asm volatile("s_waitcnt vmcnt(4)" ::: "memory");
        } else {
            asm volatile("s_waitcnt vmcnt(0)" ::: "memory");
        }
        __builtin_amdgcn_s_barrier();   // raw barrier: no compiler vmcnt(0) drain

        const signed char (*Tc)[64] = Ts[c % 3];
        const signed char (*Xc)[64] = Xs[c % 3];
        i32x4 av[4], bv[4];
#pragma unroll
        for (int t = 0; t < 4; t++) {
            av[t] = read_frag_i8(Tc, wm + t * 16 + mrow, seg);
            bv[t] = read_frag_i8(Xc, wn + t * 16 + mrow, seg);
        }
#pragma unroll
        for (int mt = 0; mt < 4; mt++)
#pragma unroll
            for (int nt = 0; nt < 4; nt++)
                acc[mt][nt] = __builtin_amdgcn_mfma_i32_16x16x64_i8(av[mt], bv[nt], acc[mt][nt], 0, 0, 0);
        __builtin_amdgcn_s_barrier();   // consumption fence before this slot is re-staged (2 iters later)
    }

    // ---- epilogue: per-row local max (int), collect candidates ----
    int tmax[4][4];
#pragma unroll
    for (int mt = 0; mt < 4; mt++)
#pragma unroll
        for (int i = 0; i < 4; i++) {
            int v = max(max(acc[mt][0][i], acc[mt][1][i]), max(acc[mt][2][i], acc[mt][3][i]));
#pragma unroll
            for (int d = 1; d < 16; d <<= 1) v = max(v, __shfl_xor(v, d));
            tmax[mt][i] = v;
        }
    if ((lane & 15) == 0) {
#pragma unroll
        for (int mt = 0; mt < 4; mt++)
#pragma unroll
            for (int i = 0; i < 4; i++)
                wtm[wave & 1][wm + mt * 16 + (lane >> 4) * 4 + i] = tmax[mt][i];
    }
    __syncthreads();
#pragma unroll
    for (int mt = 0; mt < 4; mt++)
#pragma unroll
        for (int i = 0; i < 4; i++) {
            int rl = wm + mt * 16 + (lane >> 4) * 4 + i;
            int th = max(wtm[0][rl], wtm[1][rl]) - TSCAN_I;
#pragma unroll
            for (int nt = 0; nt < 4; nt++) {
                int v = acc[mt][nt][i];
                if (v >= th) {
                    int grow = (int)qrow0 + rl;
                    int gcol = (int)krow0 + wn + nt * 16 + (lane & 15);
                    int idx = atomicAdd(&cnt[grow], 1);
                    if (idx < CAP)
                        cand[(size_t)grow * CAP + idx] = make_int2(gcol, __float_as_int((float)v * DEQ));
                }
            }
        }
}

// ---------------- rescore: exact logits for survivors (T row . X key row), softmax ----------------
__global__ __launch_bounds__(64) void k_rescore(
    const unsigned short* __restrict__ Thi, const unsigned short* __restrict__ Tlo,
    const float* __restrict__ X, const float* __restrict__ vmean,
    const int* __restrict__ cnt, const int2* __restrict__ cand,
    float* __restrict__ out) {
    int row = blockIdx.x;
    int lane = threadIdx.x;
    int c = cnt[row]; if (c > CAP) c = CAP;
    const int2* cl = cand + (size_t)row * CAP;

    float smax = -INFINITY;
    for (int j = lane; j < c; j += 64) smax = fmaxf(smax, __int_as_float(cl[j].y));
    for (int d = 1; d < 64; d <<= 1) smax = fmaxf(smax, __shfl_xor(smax, d));
    float th = smax - TRES;

    // T row (exact hi+lo) into registers: dims [lane*16, lane*16+16)
    float q[16];
    {
        const unsigned short* qh = Thi + (size_t)row * EMBED + lane * 16;
        const unsigned short* ql = Tlo + (size_t)row * EMBED + lane * 16;
        bf16x8 h0 = *(const bf16x8*)qh, h1 = *(const bf16x8*)(qh + 8);
        bf16x8 l0 = *(const bf16x8*)ql, l1 = *(const bf16x8*)(ql + 8);
#pragma unroll
        for (int i = 0; i < 8; i++) {
            q[i]     = bf2f((unsigned short)h0[i]) + bf2f((unsigned short)l0[i]);
            q[i + 8] = bf2f((unsigned short)h1[i]) + bf2f((unsigned short)l1[i]);
        }
    }

    __shared__ int   sm_[CAP];
    __shared__ float sl_[CAP];
    __shared__ int   ns_;
    if (lane == 0) ns_ = 0;
    __syncthreads();
    for (int j = lane; j < c; j += 64) {
        int2 p = cl[j];
        if (__int_as_float(p.y) >= th) {
            int idx = atomicAdd(&ns_, 1);
            sm_[idx] = p.x;
        }
    }
    __syncthreads();
    int ns = ns_;
    for (int t = 0; t < ns; t++) {
        int m = sm_[t];
        const float* xr = X + (size_t)m * EMBED + lane * 16;
        float4 a0 = *(const float4*)(xr);
        float4 a1 = *(const float4*)(xr + 4);
        float4 a2 = *(const float4*)(xr + 8);
        float4 a3 = *(const float4*)(xr + 12);
        float dp = q[0]*a0.x + q[1]*a0.y + q[2]*a0.z + q[3]*a0.w
                 + q[4]*a1.x + q[5]*a1.y + q[6]*a1.z + q[7]*a1.w
                 + q[8]*a2.x + q[9]*a2.y + q[10]*a2.z + q[11]*a2.w
                 + q[12]*a3.x + q[13]*a3.y + q[14]*a3.z + q[15]*a3.w;
        for (int d = 1; d < 64; d <<= 1) dp += __shfl_xor(dp, d);
        if (lane == 0) sl_[t] = dp * 0.03125f;
    }
    __syncthreads();
    if (lane == 0) {
        float lm = -INFINITY;
        for (int t = 0; t < ns; t++) lm = fmaxf(lm, sl_[t]);
        float den = 0.f, num = 0.f;
        for (int t = 0; t < ns; t++) {
            float e = __expf(sl_[t] - lm);
            den += e;
            num += e * vmean[sm_[t]];
        }
        out[row] = num / den;
    }
}

extern "C" void kernel_launch(void* const* d_in, const int* in_sizes, int n_in,
                              void* d_out, int out_size, void* d_ws, size_t ws_size,
                              hipStream_t stream) {
    const float* X  = (const float*)d_in[0];
    const float* Wq = (const float*)d_in[1];
    const float* Wk = (const float*)d_in[2];
    const float* Wv = (const float*)d_in[3];
    float* out = (float*)d_out;

    char* p = (char*)d_ws;
    auto alloc = [&](size_t bytes) -> void* {
        void* q = (void*)p;
        p += (bytes + 255) & ~(size_t)255;
        return q;
    };
    unsigned short* Wqhi = (unsigned short*)alloc((size_t)EMBED * EMBED * 2);
    unsigned short* Wqlo = (unsigned short*)alloc((size_t)EMBED * EMBED * 2);
    unsigned short* Wkhi = (unsigned short*)alloc((size_t)EMBED * EMBED * 2);
    unsigned short* Wklo = (unsigned short*)alloc((size_t)EMBED * EMBED * 2);
    unsigned short* MThi = (unsigned short*)alloc((size_t)EMBED * EMBED * 2);
    unsigned short* MTlo = (unsigned short*)alloc((size_t)EMBED * EMBED * 2);
    unsigned short* Xhi  = (unsigned short*)alloc((size_t)ROWS * EMBED * 2);
    unsigned short* Xlo  = (unsigned short*)alloc((size_t)ROWS * EMBED * 2);
    unsigned short* Thi  = (unsigned short*)alloc((size_t)ROWS * EMBED * 2);
    unsigned short* Tlo  = (unsigned short*)alloc((size_t)ROWS * EMBED * 2);
    signed char*    Xi8  = (signed char*)alloc((size_t)ROWS * EMBED);
    signed char*    Ti8  = (signed char*)alloc((size_t)ROWS * EMBED);
    float* wvbar = (float*)alloc(EMBED * 4);
    float* vmean = (float*)alloc((size_t)ROWS * 4);
    int*   cnt   = (int*)alloc((size_t)ROWS * 4);
    int2*  cand  = (int2*)alloc((size_t)ROWS * CAP * 8);

    k_wvbar<<<EMBED, 256, 0, stream>>>(Wv, wvbar);
    // Row splits of the ORIGINAL Wq/Wk (M contraction is over the contiguous output dim).
    // vmean + Ti8 args are scratch here (overwritten later).
    k_xsplit_vmean<<<EMBED, 256, 0, stream>>>(Wq, wvbar, Wqhi, Wqlo, Ti8, vmean);
    k_xsplit_vmean<<<EMBED, 256, 0, stream>>>(Wk, wvbar, Wkhi, Wklo, Ti8, vmean);
    // M^T[b][a] = sum_n Wk[b][n]*Wq[a][n]
    k_gemm3<<<64, 256, 0, stream>>>(Wkhi, Wklo, Wqhi, Wqlo, MThi, MTlo);
    k_xsplit_vmean<<<ROWS, 256, 0, stream>>>(X, wvbar, Xhi, Xlo, Xi8, vmean);   // real vmean + Xi8
    k_gemm3q<<<1024, 256, 0, stream>>>(Xhi, Xlo, MThi, MTlo, Thi, Tlo, Ti8);    // T = X.M (+ Ti8)
    k_zero<<<ROWS / 256, 256, 0, stream>>>(cnt);
    k_scan<<<dim3(32, 32, 4), 256, 0, stream>>>(Ti8, Xi8, cnt, cand);
    k_rescore<<<ROWS, 64, 0, stream>>>(Thi, Tlo, X, vmean, cnt, cand, out);
}